// Round 2
// 2238.504 us; speedup vs baseline: 1.1196x; 1.1196x over previous
//
#include <hip/hip_runtime.h>
#include <math.h>

#define M_NODES 1000
#define L_EDGES 499500
#define GROUPS  500      // row pairs (g, 998-g); g==499 is self-paired (row 499)
#define NG      4        // groups per chunk/block
#define CHUNKS  125      // GROUPS / NG

// LDS anti-conflict swizzle: bijective within each aligned 4-block, spreads the
// lane-stride-4 (16B) access pattern of the strip loop across banks (<=2-way).
#define IDX(i) ((i) ^ (((i) >> 5) & 3))

__device__ __forceinline__ float wave_sum(float v){
  #pragma unroll
  for (int o = 32; o > 0; o >>= 1) v += __shfl_down(v, o);
  return v;
}

__global__ __launch_bounds__(256) void init_kernel(float* __restrict__ v0, int n){
  int i = blockIdx.x * 256 + threadIdx.x;
  if (i < n) v0[i] = 0.f;
}

// Fused edge pass: C_{t-1} (w_t update, write out[t-1]) when t>=1,
// A_t (p1_t, partial DT(w_t), DT(p1_t)) when t<T.
// Core loop: 4 consecutive edges per thread on 16B-aligned boundaries ->
// float4 z/w loads, float4 w store, 4-wide ILP. <=3 boundary edges per row
// take the scalar path.
__global__ __launch_bounds__(256) void edge_pass(
    const float* __restrict__ z, float* __restrict__ out,
    const float* __restrict__ vprev, const float* __restrict__ vcur,
    const float* __restrict__ p2g,
    float* __restrict__ partA, float* __restrict__ partB,
    const float* __restrict__ gn_p, const float* __restrict__ beta_p,
    int t, int T)
{
  const int b   = blockIdx.x / CHUNKS;
  const int c   = blockIdx.x % CHUNKS;
  const int tid = threadIdx.x;
  const float gn   = gn_p[0];
  const float beta = beta_p[0];
  const float c1 = 1.f - 2.f * gn * beta;
  const float g2 = 2.f * gn;
  const bool has_c = (t >= 1);
  const bool has_a = (t < T);
  const bool has_w = (t >= 2);

  __shared__ float vp[M_NODES];  // v_{t-1}   (swizzled)
  __shared__ float vc[M_NODES];  // v_t       (swizzled)
  __shared__ float pp[M_NODES];  // p2_{t-1}  (swizzled)
  __shared__ float sA[M_NODES];  // partial DT(w_t)   (swizzled)
  __shared__ float sB[M_NODES];  // partial DT(p1_t)  (swizzled)

  for (int i = tid; i < M_NODES; i += 256){
    sA[i] = 0.f; sB[i] = 0.f;   // zeroing all slots; swizzle is a permutation
    if (has_c){ vp[IDX(i)] = vprev[b * M_NODES + i]; pp[IDX(i)] = p2g[b * M_NODES + i]; }
    if (has_a){ vc[IDX(i)] = vcur[b * M_NODES + i]; }
  }
  __syncthreads();

  const float* zb    = z + (size_t)b * L_EDGES;
  const float* wprev = has_w ? out + ((size_t)b * T + (t - 2)) * L_EDGES : nullptr;
  float*       wout  = has_c ? out + ((size_t)b * T + (t - 1)) * L_EDGES : nullptr;

  const int g0 = c * NG;
  const int g1 = (g0 + NG < GROUPS) ? (g0 + NG) : GROUPS;

  for (int g = g0; g < g1; ++g){
    #pragma unroll
    for (int half = 0; half < 2; ++half){
      const int r = half ? (998 - g) : g;
      if (half && r == g) break;          // self-paired row (g == 499)
      const int n    = 999 - r;           // edges in row r
      const int base = r * 999 - (r * (r - 1)) / 2;
      float vpr = 0.f, ppr = 0.f, vcr = 0.f;
      if (has_c){ vpr = vp[IDX(r)]; ppr = pp[IDX(r)]; }
      if (has_a){ vcr = vc[IDX(r)]; }

      float pw = 0.f, pq = 0.f;           // row-sum partials for s[r]

      // alignment decomposition of [0, n): a0 scalar + 4*strips vector + epi scalar
      const int a0m    = (4 - (base & 3)) & 3;
      const int a0     = (a0m < n) ? a0m : n;
      const int strips = (n - a0) >> 2;
      const int epi    = n - a0 - (strips << 2);

      auto edge1 = [&](int k){
        const int e = base + k;
        const int j = r + 1 + k;
        const float ze = zb[e];
        float w_new = 0.f;
        if (has_c){
          const float w_old = has_w ? wprev[e] : 0.f;
          const float y1 = w_old * c1 - gn * (vpr + vp[IDX(j)]);
          const float p1 = fmaxf(0.f, y1 - g2 * ze);
          const float q1 = p1 * c1 - gn * (ppr + pp[IDX(j)]);
          w_new = w_old - y1 + q1;
          wout[e] = w_new;
        }
        if (has_a){
          const float y1n = w_new * c1 - gn * (vcr + vc[IDX(j)]);
          const float p1n = fmaxf(0.f, y1n - g2 * ze);
          pw += w_new; pq += p1n;
          atomicAdd(&sA[IDX(j)], w_new);
          atomicAdd(&sB[IDX(j)], p1n);
        }
      };
      if (tid < a0) edge1(tid);
      if (tid >= 4 && tid < 4 + epi) edge1(a0 + (strips << 2) + (tid - 4));

      for (int s = tid; s < strips; s += 256){
        const int k = a0 + (s << 2);
        const int e = base + k;            // e % 4 == 0
        const int j = r + 1 + k;
        const float4 zv = *(const float4*)(zb + e);
        float w0, w1, w2, w3;
        if (has_c){
          float4 wv;
          if (has_w) wv = *(const float4*)(wprev + e);
          else { wv.x = 0.f; wv.y = 0.f; wv.z = 0.f; wv.w = 0.f; }
          const float y10 = wv.x * c1 - gn * (vpr + vp[IDX(j    )]);
          const float y11 = wv.y * c1 - gn * (vpr + vp[IDX(j + 1)]);
          const float y12 = wv.z * c1 - gn * (vpr + vp[IDX(j + 2)]);
          const float y13 = wv.w * c1 - gn * (vpr + vp[IDX(j + 3)]);
          const float p10 = fmaxf(0.f, y10 - g2 * zv.x);
          const float p11 = fmaxf(0.f, y11 - g2 * zv.y);
          const float p12 = fmaxf(0.f, y12 - g2 * zv.z);
          const float p13 = fmaxf(0.f, y13 - g2 * zv.w);
          const float q10 = p10 * c1 - gn * (ppr + pp[IDX(j    )]);
          const float q11 = p11 * c1 - gn * (ppr + pp[IDX(j + 1)]);
          const float q12 = p12 * c1 - gn * (ppr + pp[IDX(j + 2)]);
          const float q13 = p13 * c1 - gn * (ppr + pp[IDX(j + 3)]);
          w0 = wv.x - y10 + q10;
          w1 = wv.y - y11 + q11;
          w2 = wv.z - y12 + q12;
          w3 = wv.w - y13 + q13;
          float4 wo; wo.x = w0; wo.y = w1; wo.z = w2; wo.w = w3;
          *(float4*)(wout + e) = wo;
        } else { w0 = w1 = w2 = w3 = 0.f; }
        if (has_a){
          const float yn0 = w0 * c1 - gn * (vcr + vc[IDX(j    )]);
          const float yn1 = w1 * c1 - gn * (vcr + vc[IDX(j + 1)]);
          const float yn2 = w2 * c1 - gn * (vcr + vc[IDX(j + 2)]);
          const float yn3 = w3 * c1 - gn * (vcr + vc[IDX(j + 3)]);
          const float pn0 = fmaxf(0.f, yn0 - g2 * zv.x);
          const float pn1 = fmaxf(0.f, yn1 - g2 * zv.y);
          const float pn2 = fmaxf(0.f, yn2 - g2 * zv.z);
          const float pn3 = fmaxf(0.f, yn3 - g2 * zv.w);
          pw += (w0 + w1) + (w2 + w3);
          pq += (pn0 + pn1) + (pn2 + pn3);
          atomicAdd(&sA[IDX(j    )], w0); atomicAdd(&sB[IDX(j    )], pn0);
          atomicAdd(&sA[IDX(j + 1)], w1); atomicAdd(&sB[IDX(j + 1)], pn1);
          atomicAdd(&sA[IDX(j + 2)], w2); atomicAdd(&sB[IDX(j + 2)], pn2);
          atomicAdd(&sA[IDX(j + 3)], w3); atomicAdd(&sB[IDX(j + 3)], pn3);
        }
      }

      if (has_a){
        pw = wave_sum(pw);
        pq = wave_sum(pq);
        if ((tid & 63) == 0){
          atomicAdd(&sA[IDX(r)], pw);
          atomicAdd(&sB[IDX(r)], pq);
        }
      }
    }
  }

  if (has_a){
    __syncthreads();
    float* pA = partA + ((size_t)b * CHUNKS + c) * M_NODES;
    float* pB = partB + ((size_t)b * CHUNKS + c) * M_NODES;
    // chunk c only touches node indices >= g0
    for (int i = g0 + tid; i < M_NODES; i += 256){
      pA[i] = sA[IDX(i)];
      pB[i] = sB[IDX(i)];
    }
  }
}

// Node pass N_t: sum partials -> s_w, s_p; p2_t = prox(y2); v_{t+1} = p2 + gn*(s_p - s_w)
// 4 independent accumulator pairs -> 8 loads in flight per iteration (latency hiding
// for the 125-deep chunk loop on a small grid).
__global__ __launch_bounds__(256) void node_pass(
    const float* __restrict__ partA, const float* __restrict__ partB,
    const float* __restrict__ vin, float* __restrict__ vout,
    float* __restrict__ p2g,
    const float* __restrict__ gn_p, const float* __restrict__ alpha_p,
    int total)
{
  const int idx = blockIdx.x * 256 + threadIdx.x;
  if (idx >= total) return;
  const int b = idx / M_NODES;
  const int i = idx % M_NODES;
  const float gn = gn_p[0];
  const float alpha = alpha_p[0];

  const int cmax = (i / NG < CHUNKS - 1) ? (i / NG) : (CHUNKS - 1);
  const float* pA = partA + (size_t)b * CHUNKS * M_NODES + i;
  const float* pB = partB + (size_t)b * CHUNKS * M_NODES + i;

  float a0 = 0.f, a1 = 0.f, a2 = 0.f, a3 = 0.f;
  float b0 = 0.f, b1 = 0.f, b2 = 0.f, b3 = 0.f;
  int cc = 0;
  for (; cc + 3 <= cmax; cc += 4){
    a0 += pA[(size_t)(cc    ) * M_NODES]; b0 += pB[(size_t)(cc    ) * M_NODES];
    a1 += pA[(size_t)(cc + 1) * M_NODES]; b1 += pB[(size_t)(cc + 1) * M_NODES];
    a2 += pA[(size_t)(cc + 2) * M_NODES]; b2 += pB[(size_t)(cc + 2) * M_NODES];
    a3 += pA[(size_t)(cc + 3) * M_NODES]; b3 += pB[(size_t)(cc + 3) * M_NODES];
  }
  for (; cc <= cmax; ++cc){
    a0 += pA[(size_t)cc * M_NODES];
    b0 += pB[(size_t)cc * M_NODES];
  }
  const float sw = (a0 + a1) + (a2 + a3);
  const float sp = (b0 + b1) + (b2 + b3);

  const float v  = vin[idx];
  const float y2 = v + gn * sw;
  const float up = fmaxf(y2 * y2 + 4.f * gn * alpha, 1e-8f);
  const float p2v = 0.5f * (y2 - sqrtf(up));
  p2g[idx] = p2v;
  vout[idx] = p2v + gn * (sp - sw);
}

extern "C" void kernel_launch(void* const* d_in, const int* in_sizes, int n_in,
                              void* d_out, int out_size, void* d_ws, size_t ws_size,
                              hipStream_t stream)
{
  const float* z     = (const float*)d_in[0];
  const float* gn    = (const float*)d_in[1];
  const float* alpha = (const float*)d_in[2];
  const float* beta  = (const float*)d_in[3];
  const int B = in_sizes[0] / L_EDGES;      // 16
  const int T = out_size / in_sizes[0];     // 15
  float* out = (float*)d_out;

  float* ws    = (float*)d_ws;
  float* v0    = ws;                                   // B*M
  float* v1    = v0 + (size_t)B * M_NODES;             // B*M
  float* p2g   = v1 + (size_t)B * M_NODES;             // B*M
  float* partA = p2g + (size_t)B * M_NODES;            // B*CHUNKS*M
  float* partB = partA + (size_t)B * CHUNKS * M_NODES; // B*CHUNKS*M

  const int total = B * M_NODES;
  const int nodeBlocks = (total + 255) / 256;
  hipLaunchKernelGGL(init_kernel, dim3(nodeBlocks), dim3(256), 0, stream, v0, total);

  float* vbuf[2] = { v0, v1 };
  const dim3 egrid(B * CHUNKS);

  // t=0: A-only (w_0=0).  t=1..T-1: fused C_{t-1}+A_t.  t=T: C-only (final write).
  for (int t = 0; t <= T; ++t){
    const float* vprev = vbuf[((t - 1) + 2) % 2];  // v_{t-1} (unused at t=0)
    const float* vcur  = vbuf[t % 2];              // v_t     (unused at t=T)
    hipLaunchKernelGGL(edge_pass, egrid, dim3(256), 0, stream,
                       z, out, vprev, vcur, p2g, partA, partB, gn, beta, t, T);
    if (t < T){
      hipLaunchKernelGGL(node_pass, dim3(nodeBlocks), dim3(256), 0, stream,
                         partA, partB, vbuf[t % 2], vbuf[(t + 1) % 2], p2g,
                         gn, alpha, total);
    }
  }
}